// Round 7
// baseline (852.540 us; speedup 1.0000x reference)
//
#include <hip/hip_runtime.h>
#include <hip/hip_bf16.h>

// Round 7: fp32 inputs, fp32 output (established by R5/R6 dtype bisection).
// Internals in bf16 MFMA; fp32 accumulate; fp32 final epilogue.

#define S_LEN 2048

typedef __hip_bfloat16 bf16;
using bf16x8 = __attribute__((ext_vector_type(8))) __bf16;
using f32x4  = __attribute__((ext_vector_type(4))) float;

__device__ inline unsigned short bf16_bits(float f) {
    union { __hip_bfloat16 h; unsigned short u; } cv;
    cv.h = __float2bfloat16(f);
    return cv.u;
}

// load 8 consecutive fp32, convert RNE to a bf16x8 fragment
__device__ inline bf16x8 load_cvt8(const float* __restrict__ p) {
    f32x4 a = *(const f32x4*)p;
    f32x4 b = *(const f32x4*)(p + 4);
    union { bf16x8 v; unsigned short u[8]; } r;
    r.u[0] = bf16_bits(a[0]); r.u[1] = bf16_bits(a[1]);
    r.u[2] = bf16_bits(a[2]); r.u[3] = bf16_bits(a[3]);
    r.u[4] = bf16_bits(b[0]); r.u[5] = bf16_bits(b[1]);
    r.u[6] = bf16_bits(b[2]); r.u[7] = bf16_bits(b[3]);
    return r.v;
}

// ---------------- weight transpose + fp32->bf16: out[n][k] = (bf16)in[k][n] ----
__global__ __launch_bounds__(256) void transpose_k(const float* __restrict__ in,
                                                   bf16* __restrict__ out,
                                                   int R, int C) {
    __shared__ float tile[32][33];
    int tx = threadIdx.x & 31, ty = threadIdx.x >> 5;  // ty 0..7
    int r0 = blockIdx.y * 32, c0 = blockIdx.x * 32;
#pragma unroll
    for (int p = 0; p < 4; ++p)
        tile[ty + p * 8][tx] = in[(size_t)(r0 + ty + p * 8) * C + c0 + tx];
    __syncthreads();
#pragma unroll
    for (int p = 0; p < 4; ++p)
        out[(size_t)(c0 + ty + p * 8) * R + r0 + tx] = __float2bfloat16(tile[tx][ty + p * 8]);
}

// ---------------- GEMM: C = A[M,K] * Bt[N,K]^T (bf16 MFMA, fp32 acc)
// a_fp32: A is fp32 (converted during LDS staging) else bf16.
// mode 0: bf16 row-major C. mode 1: V-transpose epilogue into Vt[b][hkv][d][s].
// mode 2: fp32 row-major C.
__global__ __launch_bounds__(256) void gemm_k(const void* __restrict__ Av,
                                              const bf16* __restrict__ Bt,
                                              void* __restrict__ Cv,
                                              int M, int N, int K, int mode, int a_fp32) {
    __shared__ bf16 As[128 * 40];
    __shared__ bf16 Bs[128 * 40];
    int tid  = threadIdx.x;
    int lane = tid & 63, wave = tid >> 6;
    int quad = lane >> 4, r = lane & 15;
    int wm = (wave >> 1) * 64, wn = (wave & 1) * 64;
    int m0 = blockIdx.y * 128, n0 = blockIdx.x * 128;

    f32x4 acc[4][4];
#pragma unroll
    for (int i = 0; i < 4; ++i)
#pragma unroll
        for (int j = 0; j < 4; ++j) acc[i][j] = (f32x4)0.0f;

    int srow = tid >> 2;            // 0..63
    int skc  = (tid & 3) << 3;      // 0,8,16,24

    const float* Af = (const float*)Av;
    const bf16*  Ab = (const bf16*)Av;

    for (int k0 = 0; k0 < K; k0 += 32) {
        __syncthreads();
        if (a_fp32) {
            *(bf16x8*)&As[srow * 40 + skc]        = load_cvt8(Af + (size_t)(m0 + srow) * K + k0 + skc);
            *(bf16x8*)&As[(srow + 64) * 40 + skc] = load_cvt8(Af + (size_t)(m0 + srow + 64) * K + k0 + skc);
        } else {
            *(bf16x8*)&As[srow * 40 + skc]        = *(const bf16x8*)(Ab + (size_t)(m0 + srow) * K + k0 + skc);
            *(bf16x8*)&As[(srow + 64) * 40 + skc] = *(const bf16x8*)(Ab + (size_t)(m0 + srow + 64) * K + k0 + skc);
        }
        *(bf16x8*)&Bs[srow * 40 + skc]        = *(const bf16x8*)(Bt + (size_t)(n0 + srow) * K + k0 + skc);
        *(bf16x8*)&Bs[(srow + 64) * 40 + skc] = *(const bf16x8*)(Bt + (size_t)(n0 + srow + 64) * K + k0 + skc);
        __syncthreads();
        bf16x8 af[4], bfr[4];
#pragma unroll
        for (int mt = 0; mt < 4; ++mt) af[mt]  = *(const bf16x8*)&As[(wm + mt * 16 + r) * 40 + quad * 8];
#pragma unroll
        for (int nt = 0; nt < 4; ++nt) bfr[nt] = *(const bf16x8*)&Bs[(wn + nt * 16 + r) * 40 + quad * 8];
#pragma unroll
        for (int mt = 0; mt < 4; ++mt)
#pragma unroll
            for (int nt = 0; nt < 4; ++nt)
                acc[mt][nt] = __builtin_amdgcn_mfma_f32_16x16x32_bf16(af[mt], bfr[nt], acc[mt][nt], 0, 0, 0);
    }

    if (mode == 0) {
        bf16* C = (bf16*)Cv;
#pragma unroll
        for (int mt = 0; mt < 4; ++mt)
#pragma unroll
            for (int nt = 0; nt < 4; ++nt) {
                int row = m0 + wm + mt * 16 + quad * 4;
                int col = n0 + wn + nt * 16 + r;
#pragma unroll
                for (int i = 0; i < 4; ++i)
                    C[(size_t)(row + i) * N + col] = __float2bfloat16(acc[mt][nt][i]);
            }
    } else if (mode == 1) {
        // Vt[b][hkv][d][s]: flat = (b*512 + col)*2048 + s ; 4 consecutive tokens per lane
        unsigned short* C = (unsigned short*)Cv;
#pragma unroll
        for (int mt = 0; mt < 4; ++mt)
#pragma unroll
            for (int nt = 0; nt < 4; ++nt) {
                int rowb = m0 + wm + mt * 16 + quad * 4;
                int col  = n0 + wn + nt * 16 + r;
                int b = rowb >> 11, s = rowb & 2047;
                ushort4 pk;
                pk.x = bf16_bits(acc[mt][nt][0]);
                pk.y = bf16_bits(acc[mt][nt][1]);
                pk.z = bf16_bits(acc[mt][nt][2]);
                pk.w = bf16_bits(acc[mt][nt][3]);
                *(ushort4*)(C + (size_t)(b * 512 + col) * 2048 + s) = pk;
            }
    } else {
        float* C = (float*)Cv;
#pragma unroll
        for (int mt = 0; mt < 4; ++mt)
#pragma unroll
            for (int nt = 0; nt < 4; ++nt) {
                int row = m0 + wm + mt * 16 + quad * 4;
                int col = n0 + wn + nt * 16 + r;
#pragma unroll
                for (int i = 0; i < 4; ++i)
                    C[(size_t)(row + i) * N + col] = acc[mt][nt][i];
            }
    }
}

// ---------------- flash attention (GQA), one (b, h, 64-row q-tile) per block
// Qin: [B,S,2048] bf16 (h*64+d), K: [B,S,512] bf16, Vt: [B][8][64][S] bf16
// Aout: [B,S,2048] bf16
__global__ __launch_bounds__(256) void attn_k(const bf16* __restrict__ Qin,
                                              const bf16* __restrict__ Kb,
                                              const bf16* __restrict__ Vt,
                                              bf16* __restrict__ Aout) {
    __shared__ bf16 Pl[4][16 * 40];   // per-wave P round-trip (C-layout -> A-layout)
    int tid = threadIdx.x, lane = tid & 63, w = tid >> 6;
    int quad = lane >> 4, r = lane & 15;
    int qt = blockIdx.x, h = blockIdx.y, b = blockIdx.z;
    int hk = h >> 2;
    int q0 = qt * 64 + w * 16;

    bf16x8 qf[2];
#pragma unroll
    for (int f = 0; f < 2; ++f)
        qf[f] = *(const bf16x8*)(Qin + (size_t)(b * S_LEN + q0 + r) * 2048 + h * 64 + f * 32 + quad * 8);

    const bf16* Kbase = Kb + (size_t)b * S_LEN * 512 + hk * 64;
    const bf16* Vbase = Vt + (size_t)(b * 512 + hk * 64) * 2048;

    f32x4 oacc[4];
#pragma unroll
    for (int dt = 0; dt < 4; ++dt) oacc[dt] = (f32x4)0.0f;
    float m_i[4], l_i[4];
#pragma unroll
    for (int i = 0; i < 4; ++i) { m_i[i] = -INFINITY; l_i[i] = 0.0f; }

    for (int k0 = 0; k0 < S_LEN; k0 += 32) {
        f32x4 s0 = (f32x4)0.0f, s1 = (f32x4)0.0f;
        bf16x8 kf0 = *(const bf16x8*)(Kbase + (size_t)(k0 + r) * 512 + quad * 8);
        bf16x8 kf1 = *(const bf16x8*)(Kbase + (size_t)(k0 + r) * 512 + 32 + quad * 8);
        bf16x8 kf2 = *(const bf16x8*)(Kbase + (size_t)(k0 + 16 + r) * 512 + quad * 8);
        bf16x8 kf3 = *(const bf16x8*)(Kbase + (size_t)(k0 + 16 + r) * 512 + 32 + quad * 8);
        s0 = __builtin_amdgcn_mfma_f32_16x16x32_bf16(qf[0], kf0, s0, 0, 0, 0);
        s0 = __builtin_amdgcn_mfma_f32_16x16x32_bf16(qf[1], kf1, s0, 0, 0, 0);
        s1 = __builtin_amdgcn_mfma_f32_16x16x32_bf16(qf[0], kf2, s1, 0, 0, 0);
        s1 = __builtin_amdgcn_mfma_f32_16x16x32_bf16(qf[1], kf3, s1, 0, 0, 0);

        float alpha[4];
#pragma unroll
        for (int i = 0; i < 4; ++i) {
            float a  = s0[i] * 0.125f;
            float c2 = s1[i] * 0.125f;
            float mt_ = fmaxf(a, c2);
#pragma unroll
            for (int d2 = 1; d2 < 16; d2 <<= 1) mt_ = fmaxf(mt_, __shfl_xor(mt_, d2));
            float mnew = fmaxf(m_i[i], mt_);
            float p0 = __expf(a - mnew), p1 = __expf(c2 - mnew);
            float rs = p0 + p1;
#pragma unroll
            for (int d2 = 1; d2 < 16; d2 <<= 1) rs += __shfl_xor(rs, d2);
            alpha[i] = __expf(m_i[i] - mnew);
            l_i[i] = l_i[i] * alpha[i] + rs;
            m_i[i] = mnew;
            Pl[w][(quad * 4 + i) * 40 + r]      = __float2bfloat16(p0);
            Pl[w][(quad * 4 + i) * 40 + 16 + r] = __float2bfloat16(p1);
        }
        __syncthreads();
        bf16x8 pf = *(const bf16x8*)&Pl[w][r * 40 + quad * 8];
        __syncthreads();
#pragma unroll
        for (int dt = 0; dt < 4; ++dt) {
            bf16x8 vf = *(const bf16x8*)(Vbase + (size_t)(dt * 16 + r) * 2048 + k0 + quad * 8);
            f32x4 o = oacc[dt];
#pragma unroll
            for (int i = 0; i < 4; ++i) o[i] *= alpha[i];
            oacc[dt] = __builtin_amdgcn_mfma_f32_16x16x32_bf16(pf, vf, o, 0, 0, 0);
        }
    }
#pragma unroll
    for (int dt = 0; dt < 4; ++dt)
#pragma unroll
        for (int i = 0; i < 4; ++i) {
            float v = oacc[dt][i] / l_i[i];
            Aout[(size_t)(b * S_LEN + q0 + quad * 4 + i) * 2048 + h * 64 + dt * 16 + r] = __float2bfloat16(v);
        }
}

extern "C" void kernel_launch(void* const* d_in, const int* in_sizes, int n_in,
                              void* d_out, int out_size, void* d_ws, size_t ws_size,
                              hipStream_t stream) {
    const float* x  = (const float*)d_in[0];
    const float* wq = (const float*)d_in[1];
    const float* wk = (const float*)d_in[2];
    const float* wv = (const float*)d_in[3];
    const float* wo = (const float*)d_in[4];
    char* ws = (char*)d_ws;

    // d_out is 32 MB fp32. Park bf16 Q (16 MB) in its first half; the final
    // GEMM overwrites all of d_out with fp32 results afterwards.
    // ws (24 MB, phased):
    //   phase 1: [0,8M)=wqT [8,10M)=wkT [10,12M)=wvT
    //   phase 2: [0,16M)=attnOut(bf16)  [16,20M)=Kb  [20,24M)=Vt
    //   phase 3: [0,16M)=attnOut        [16,24M)=woT
    bf16* wqT  = (bf16*)(ws + 0);
    bf16* wkT  = (bf16*)(ws + 8388608);
    bf16* wvT  = (bf16*)(ws + 10485760);
    bf16* attn = (bf16*)(ws + 0);
    bf16* Kb   = (bf16*)(ws + 16777216);
    bf16* Vtb  = (bf16*)(ws + 20971520);
    bf16* woT  = (bf16*)(ws + 16777216);
    bf16* Qb   = (bf16*)d_out;

    transpose_k<<<dim3(64, 64), 256, 0, stream>>>(wq, wqT, 2048, 2048);
    transpose_k<<<dim3(16, 64), 256, 0, stream>>>(wk, wkT, 2048, 512);
    transpose_k<<<dim3(16, 64), 256, 0, stream>>>(wv, wvT, 2048, 512);

    gemm_k<<<dim3(16, 32), 256, 0, stream>>>(x, wqT, Qb, 4096, 2048, 2048, 0, 1);
    gemm_k<<<dim3(4, 32), 256, 0, stream>>>(x, wkT, Kb, 4096, 512, 2048, 0, 1);
    gemm_k<<<dim3(4, 32), 256, 0, stream>>>(x, wvT, Vtb, 4096, 512, 2048, 1, 1);

    attn_k<<<dim3(32, 32, 2), 256, 0, stream>>>(Qb, Kb, Vtb, attn);

    // Kb/Vt dead; put woT in their slot
    transpose_k<<<dim3(64, 64), 256, 0, stream>>>(wo, woT, 2048, 2048);

    // fp32 epilogue into d_out
    gemm_k<<<dim3(16, 32), 256, 0, stream>>>(attn, woT, d_out, 4096, 2048, 2048, 2, 0);
}